// Round 1
// baseline (1246.715 us; speedup 1.0000x reference)
//
#include <hip/hip_runtime.h>
#include <math.h>

// ---- problem constants ----
#define NH      32
#define DDIM    128
#define KVLEN   32768
#define PAGESZ  16
#define NPAGES  2048          // KVLEN / PAGESZ
#define TOPK    256
#define HDIM    4096
#define NSLICE  64            // split-K slices for GEMVs (64 rows each)

// ---- workspace layout (in floats) ----
// partial1 : 3 * NSLICE * 4096          = 786432
// qkv      : 3 * 4096                   = 12288   (q | k_new | v_new, q/k roped)
// est      : 32 * 2048                  = 65536
// top_idx  : 32 * 256 ints              = 8192
// pm       : 4096
// pl       : 4096
// po       : 4096 * 128                 = 524288
// o_final  : 4096
// partial2 : NSLICE * 4096              = 262144
#define OFF_PARTIAL1 0
#define OFF_QKV      786432
#define OFF_EST      798720
#define OFF_TIDX     864256
#define OFF_PM       872448
#define OFF_PL       876544
#define OFF_PO       880640
#define OFF_OFINAL   1404928
#define OFF_PARTIAL2 1409024

#define ATTN_SCALE 0.08838834764831845f  // 1/sqrt(128)

__device__ __forceinline__ float wave_reduce64(float v) {
  #pragma unroll
  for (int off = 32; off > 0; off >>= 1) v += __shfl_xor(v, off, 64);
  return v;
}

// ---------------- GEMV x @ {Wq,Wk,Wv} : split-K partials ----------------
__global__ __launch_bounds__(256) void gemv_qkv_kernel(
    const float* __restrict__ x, const float* __restrict__ Wq,
    const float* __restrict__ Wk, const float* __restrict__ Wv,
    float* __restrict__ partial) {
  const int b  = blockIdx.x;            // 768 = 3 mats * 64 slices * 4 colblocks
  const int cb = b & 3;
  const int rs = (b >> 2) & 63;
  const int m  = b >> 8;
  const float* __restrict__ W = (m == 0) ? Wq : (m == 1) ? Wk : Wv;
  const int c0 = cb * 1024 + threadIdx.x * 4;
  float4 acc = make_float4(0.f, 0.f, 0.f, 0.f);
  const int r0 = rs * 64;
  #pragma unroll 4
  for (int r = r0; r < r0 + 64; ++r) {
    const float xv = x[r];
    const float4 w = *reinterpret_cast<const float4*>(W + (size_t)r * HDIM + c0);
    acc.x += xv * w.x; acc.y += xv * w.y; acc.z += xv * w.z; acc.w += xv * w.w;
  }
  *reinterpret_cast<float4*>(partial + (size_t)(m * NSLICE + rs) * HDIM + c0) = acc;
}

// -------- reduce split-K partials + RoPE(q, k_new) ----------
__global__ __launch_bounds__(256) void reduce_qkv_rope_kernel(
    const float* __restrict__ partial, float* __restrict__ qkv) {
  const int t = blockIdx.x * 256 + threadIdx.x;   // 12288 threads
  const int m = t >> 12;
  const int c = t & 4095;
  const float* __restrict__ p = partial + (size_t)m * NSLICE * HDIM + c;
  float s = 0.f;
  #pragma unroll 8
  for (int i = 0; i < NSLICE; ++i) s += p[i * HDIM];
  float out;
  if (m == 2) {
    out = s;                                       // v_new: no rope
  } else {
    const int d  = c & 127;
    const int dd = d & 63;
    const int pc = (d < 64) ? (c + 64) : (c - 64);
    const float* __restrict__ pp = partial + (size_t)m * NSLICE * HDIM + pc;
    float sp = 0.f;
    #pragma unroll 8
    for (int i = 0; i < NSLICE; ++i) sp += pp[i * HDIM];
    // mimic reference f32 rounding: f32 inv_freq -> f32 angle -> sinf/cosf
    const float t10 = (float)pow(10000.0, (double)dd / 64.0);
    const float inv = 1.0f / t10;
    const float ang = 32768.0f * inv;              // pos = float(KV)
    const float cs = cosf(ang), sn = sinf(ang);
    out = (d < 64) ? (s * cs - sp * sn) : (s * cs + sp * sn);
  }
  qkv[t] = out;
}

// -------- fused page min/max + quest score bound: est[h][p] --------
__global__ __launch_bounds__(256) void est_kernel(
    const float* __restrict__ kc, const float* __restrict__ q,
    float* __restrict__ est) {
  const int p   = blockIdx.x;     // page
  const int tid = threadIdx.x;
  __shared__ float qs[HDIM];
  for (int i = tid; i < HDIM / 4; i += 256)
    reinterpret_cast<float4*>(qs)[i] = reinterpret_cast<const float4*>(q)[i];
  __syncthreads();
  const float4* __restrict__ base =
      reinterpret_cast<const float4*>(kc + (size_t)p * PAGESZ * HDIM);
  float4 mn[4], mx[4];
  #pragma unroll
  for (int k = 0; k < 4; ++k) { mn[k] = mx[k] = base[tid + 256 * k]; }
  for (int j = 1; j < PAGESZ; ++j) {
    #pragma unroll
    for (int k = 0; k < 4; ++k) {
      const float4 v = base[j * 1024 + tid + 256 * k];
      mn[k].x = fminf(mn[k].x, v.x); mx[k].x = fmaxf(mx[k].x, v.x);
      mn[k].y = fminf(mn[k].y, v.y); mx[k].y = fmaxf(mx[k].y, v.y);
      mn[k].z = fminf(mn[k].z, v.z); mx[k].z = fmaxf(mx[k].z, v.z);
      mn[k].w = fminf(mn[k].w, v.w); mx[k].w = fmaxf(mx[k].w, v.w);
    }
  }
  #pragma unroll
  for (int k = 0; k < 4; ++k) {
    const int chunk = tid + 256 * k;           // float4 index; head = chunk>>5
    const float* __restrict__ qf = qs + chunk * 4;
    float s = fmaxf(qf[0] * mn[k].x, qf[0] * mx[k].x)
            + fmaxf(qf[1] * mn[k].y, qf[1] * mx[k].y)
            + fmaxf(qf[2] * mn[k].z, qf[2] * mx[k].z)
            + fmaxf(qf[3] * mn[k].w, qf[3] * mx[k].w);
    #pragma unroll
    for (int off = 16; off > 0; off >>= 1) s += __shfl_xor(s, off, 32);
    if ((tid & 31) == 0) est[(size_t)(chunk >> 5) * NPAGES + p] = s;
  }
}

// -------- exact top-256-of-2048 per head: 4-pass radix select --------
__global__ __launch_bounds__(256) void topk_kernel(
    const float* __restrict__ est, int* __restrict__ top_idx) {
  const int h   = blockIdx.x;
  const int tid = threadIdx.x;
  __shared__ unsigned u[NPAGES];
  __shared__ int hist[256];
  __shared__ int s_b, s_krem, s_cnt;
  for (int i = tid; i < NPAGES; i += 256) {
    unsigned v = __float_as_uint(est[(size_t)h * NPAGES + i]);
    v = (v & 0x80000000u) ? ~v : (v | 0x80000000u);  // orderable
    u[i] = v;
  }
  __syncthreads();
  unsigned prefix = 0;
  int krem = TOPK;
  for (int shift = 24; shift >= 0; shift -= 8) {
    hist[tid] = 0;
    __syncthreads();
    const unsigned pmask = (shift == 24) ? 0u : (0xFFFFFFFFu << (shift + 8));
    for (int i = tid; i < NPAGES; i += 256) {
      const unsigned v = u[i];
      if ((v & pmask) == prefix) atomicAdd(&hist[(v >> shift) & 255], 1);
    }
    __syncthreads();
    if (tid == 0) {
      int c = 0, b = 255;
      for (; b > 0; --b) {
        if (c + hist[b] >= krem) break;
        c += hist[b];
      }
      s_b = b; s_krem = krem - c;
    }
    __syncthreads();
    prefix |= ((unsigned)s_b) << shift;
    krem = s_krem;
    __syncthreads();
  }
  const unsigned T = prefix;   // exact threshold; krem = #ties to take
  if (tid == 0) s_cnt = 0;
  __syncthreads();
  int* __restrict__ outh = top_idx + h * TOPK;
  for (int i = tid; i < NPAGES; i += 256) {
    if (u[i] > T) { const int pos = atomicAdd(&s_cnt, 1); outh[pos] = i; }
  }
  __syncthreads();
  if (tid == 0) {
    int pos = s_cnt;
    for (int i = 0; i < NPAGES && pos < TOPK; ++i)
      if (u[i] == T) outh[pos++] = i;
  }
}

// -------- sparse flash attention: per-(head,chunk) partials --------
__global__ __launch_bounds__(256) void attn_kernel(
    const float* __restrict__ kc, const float* __restrict__ vc,
    const float* __restrict__ qkv, const int* __restrict__ top_idx,
    float* __restrict__ pm, float* __restrict__ pl, float* __restrict__ po) {
  const int bx = blockIdx.x;         // 1024 = 32 heads * 32 chunks
  const int h = bx >> 5, chunk = bx & 31;
  const int wave = threadIdx.x >> 6, lane = threadIdx.x & 63;
  const float2 q2 = reinterpret_cast<const float2*>(qkv + h * DDIM)[lane];
  const int* __restrict__ ti = top_idx + h * TOPK + chunk * 8 + wave * 2;
  float m = -INFINITY, l = 0.f;
  float2 acc = make_float2(0.f, 0.f);
  for (int t = 0; t < 32; ++t) {     // 2 pages * 16 tokens per wave
    const int page = ti[t >> 4];
    const int tok  = page * PAGESZ + (t & 15);
    const float2 k2 =
        reinterpret_cast<const float2*>(kc + ((size_t)tok * NH + h) * DDIM)[lane];
    float d = q2.x * k2.x + q2.y * k2.y;
    d = wave_reduce64(d);
    const float s    = d * ATTN_SCALE;
    const float mn   = fmaxf(m, s);
    const float corr = __expf(m - mn);
    const float pw   = __expf(s - mn);
    const float2 v2 =
        reinterpret_cast<const float2*>(vc + ((size_t)tok * NH + h) * DDIM)[lane];
    acc.x = acc.x * corr + pw * v2.x;
    acc.y = acc.y * corr + pw * v2.y;
    l = l * corr + pw;
    m = mn;
  }
  const int pidx = ((h * 32 + chunk) << 2) + wave;
  reinterpret_cast<float2*>(po + (size_t)pidx * DDIM)[lane] = acc;
  if (lane == 0) { pm[pidx] = m; pl[pidx] = l; }
}

// -------- combine partials + new-token logit -> o_final --------
__global__ __launch_bounds__(128) void attn_reduce_kernel(
    const float* __restrict__ pm, const float* __restrict__ pl,
    const float* __restrict__ po, const float* __restrict__ qkv,
    float* __restrict__ o_final) {
  const int h = blockIdx.x, d = threadIdx.x;   // 128 threads
  __shared__ float sh[DDIM];
  const float* __restrict__ pmh = pm + h * DDIM;
  const float* __restrict__ plh = pl + h * DDIM;
  float M = -INFINITY;
  for (int i = 0; i < 128; ++i) M = fmaxf(M, pmh[i]);
  float o = 0.f, l = 0.f;
  for (int i = 0; i < 128; ++i) {
    const float w = __expf(pmh[i] - M);
    o += w * po[(size_t)(h * 128 + i) * DDIM + d];
    l += w * plh[i];
  }
  sh[d] = qkv[h * DDIM + d] * qkv[HDIM + h * DDIM + d];  // q . k_new partial
  __syncthreads();
  #pragma unroll
  for (int off = 64; off > 0; off >>= 1) {
    if (d < off) sh[d] += sh[d + off];
    __syncthreads();
  }
  const float s_new = sh[0] * ATTN_SCALE;
  const float mt = fmaxf(M, s_new);
  const float cw = __expf(M - mt);
  const float pn = __expf(s_new - mt);
  o = o * cw + pn * qkv[2 * HDIM + h * DDIM + d];   // + p_new * v_new
  l = l * cw + pn;
  o_final[h * DDIM + d] = o / l;
}

// ---------------- GEMV o_final @ Wo : split-K partials ----------------
__global__ __launch_bounds__(256) void gemv_o_kernel(
    const float* __restrict__ ov, const float* __restrict__ Wo,
    float* __restrict__ partial) {
  const int b  = blockIdx.x;     // 256 = 64 slices * 4 colblocks
  const int cb = b & 3;
  const int rs = b >> 2;
  const int c0 = cb * 1024 + threadIdx.x * 4;
  float4 acc = make_float4(0.f, 0.f, 0.f, 0.f);
  const int r0 = rs * 64;
  #pragma unroll 4
  for (int r = r0; r < r0 + 64; ++r) {
    const float xv = ov[r];
    const float4 w = *reinterpret_cast<const float4*>(Wo + (size_t)r * HDIM + c0);
    acc.x += xv * w.x; acc.y += xv * w.y; acc.z += xv * w.z; acc.w += xv * w.w;
  }
  *reinterpret_cast<float4*>(partial + (size_t)rs * HDIM + c0) = acc;
}

__global__ __launch_bounds__(256) void reduce_out_kernel(
    const float* __restrict__ partial, float* __restrict__ out) {
  const int c = blockIdx.x * 256 + threadIdx.x;  // 4096
  float s = 0.f;
  #pragma unroll 8
  for (int i = 0; i < NSLICE; ++i) s += partial[(size_t)i * HDIM + c];
  out[c] = s;
}

extern "C" void kernel_launch(void* const* d_in, const int* in_sizes, int n_in,
                              void* d_out, int out_size, void* d_ws, size_t ws_size,
                              hipStream_t stream) {
  const float* x   = (const float*)d_in[0];
  const float* kc  = (const float*)d_in[1];
  const float* vc  = (const float*)d_in[2];
  const float* Wq  = (const float*)d_in[3];
  const float* Wk  = (const float*)d_in[4];
  const float* Wv  = (const float*)d_in[5];
  const float* Wo  = (const float*)d_in[6];
  float* out = (float*)d_out;
  float* ws  = (float*)d_ws;

  float* partial1 = ws + OFF_PARTIAL1;
  float* qkv      = ws + OFF_QKV;
  float* est      = ws + OFF_EST;
  int*   tidx     = (int*)(ws + OFF_TIDX);
  float* pm       = ws + OFF_PM;
  float* pl       = ws + OFF_PL;
  float* po       = ws + OFF_PO;
  float* o_final  = ws + OFF_OFINAL;
  float* partial2 = ws + OFF_PARTIAL2;

  gemv_qkv_kernel<<<768, 256, 0, stream>>>(x, Wq, Wk, Wv, partial1);
  reduce_qkv_rope_kernel<<<48, 256, 0, stream>>>(partial1, qkv);
  est_kernel<<<NPAGES, 256, 0, stream>>>(kc, qkv, est);
  topk_kernel<<<NH, 256, 0, stream>>>(est, tidx);
  attn_kernel<<<NH * 32, 256, 0, stream>>>(kc, vc, qkv, tidx, pm, pl, po);
  attn_reduce_kernel<<<NH, 128, 0, stream>>>(pm, pl, po, qkv, o_final);
  gemv_o_kernel<<<256, 256, 0, stream>>>(o_final, Wo, partial2);
  reduce_out_kernel<<<16, 256, 0, stream>>>(partial2, out);
}